// Round 6
// baseline (350.241 us; speedup 1.0000x reference)
//
#include <hip/hip_runtime.h>
#include <stdint.h>

typedef unsigned short u16;
typedef __attribute__((ext_vector_type(8))) __bf16 bf16x8;
typedef __attribute__((ext_vector_type(8))) u16 u16x8;
typedef __attribute__((ext_vector_type(4))) float f32x4;

#define T_LEN 2048
#define NB 16

__device__ __forceinline__ u16 f2bf(float f){
  uint32_t x = __builtin_bit_cast(uint32_t, f);
  x += 0x7FFFu + ((x >> 16) & 1u);
  return (u16)(x >> 16);
}

// joint -> (body part, index within part, part length)
__constant__ int c_part[17] = {1,2,3,1,1,4,4,5,5,2,2,3,3,0,0,0,0};
__constant__ int c_pidx[17] = {0,0,0,1,2,0,1,0,1,1,2,1,2,0,1,2,3};
__constant__ int c_plen[17] = {3,3,3,3,3,2,2,2,2,3,3,3,3,4,4,4,4};

// ---- poses fp32 [n][t][51] -> bf16 X0 [n][t][56]; cols 51-55 zero ----
__global__ void conv_poses(const float* __restrict__ poses, u16* __restrict__ X0)
{
  int e = blockIdx.x * 256 + threadIdx.x;          // < 16*2048*56 exact (grid 7168)
  int row = e / 56, c = e - row * 56;
  u16 v = 0;
  if (c < 51) v = f2bf(poses[row * 51 + c]);
  X0[e] = v;
}

// ---- prep_A: per-stage effective weights (fp32, dual layouts) + W4 fragments + biases.
// W1e[(p*9+d1)*51+u], W1eT[(d1*51+u)*272+p]    p<272, d1<9, u<51
// W2e[(o*9+d2)*272+pp], W2eT[(d2*272+pp)*96+o] o<96, d2<9, pp<272
// W3e[q*480 + d3*96 + o]                        q<16, d3<5, o<96
// W4f = bf16 MFMA fragments (stage 4)
__global__ void prep_A(
  const float* __restrict__ w1, const float* __restrict__ A1, const float* __restrict__ g1, const float* __restrict__ v1,
  const float* __restrict__ w2, const float* __restrict__ A2, const float* __restrict__ g2, const float* __restrict__ v2,
  const float* __restrict__ w3, const float* __restrict__ g3, const float* __restrict__ v3,
  const float* __restrict__ w4, const float* __restrict__ g4, const float* __restrict__ v4,
  const float* b1, const float* be1, const float* m1,
  const float* b2, const float* be2, const float* m2,
  const float* b3, const float* be3, const float* m3,
  const float* b4, const float* be4, const float* m4,
  float* __restrict__ W1e, float* __restrict__ W1eT,
  float* __restrict__ W2e, float* __restrict__ W2eT,
  float* __restrict__ W3e, u16* __restrict__ W4f,
  float* bias1f, float* bias2f, float* bias3f, float* bias4f)
{
  const int bid = blockIdx.x;
  const int tid = threadIdx.x;
  if (bid < 488){
    int idx = bid * 256 + tid;
    if (idx < 124848){
      int p = idx / 459, rem = idx - p * 459;
      int d1 = rem / 51, u = rem - d1 * 51;
      int c = p / 17, w = p - c * 17;
      int uj = u / 3, ci = u - uj * 3;
      float val = 0.f;
      for (int kk = 0; kk < 5; ++kk)
        for (int dv = 0; dv < 5; ++dv){
          int v = uj - dv + 2;
          if (v >= 0 && v < 17)
            val += w1[(kk*16 + c)*135 + ci*45 + d1*5 + dv] * A1[kk*289 + v*17 + w];
        }
      val *= g1[p] * rsqrtf(v1[p] + 1e-5f);
      W1e[idx] = val;
      W1eT[(d1*51 + u)*272 + p] = val;
    }
  } else if (bid < 1406){
    int idx = (bid - 488) * 256 + tid;               // < 235008 exact
    int o = idx / 2448, rem = idx - o * 2448;
    int d2 = rem / 272, pp = rem - d2 * 272;
    int c2 = o / 6, w2i = o - c2 * 6;
    int f = pp / 17, J = pp - f * 17;
    int pt = c_part[J];
    int ci = f * c_plen[J] + c_pidx[J];
    float val = 0.f;
    for (int kk = 0; kk < 5; ++kk)
      for (int dv = 0; dv < 3; ++dv){
        int v = pt - dv + 1;
        if (v >= 0 && v < 6)
          val += w2[(kk*16 + c2)*1728 + ci*27 + d2*3 + dv] * A2[kk*36 + v*6 + w2i];
      }
    val *= g2[o] * rsqrtf(v2[o] + 1e-5f);
    W2e[idx] = val;                                   // idx == (o*9+d2)*272+pp
    W2eT[(d2*272 + pp)*96 + o] = val;
  } else if (bid < 1436){
    int idx = (bid - 1406) * 256 + tid;              // < 7680 exact
    int q = idx / 480, rem = idx - q * 480;
    int d3 = rem / 96, o = rem - d3 * 96;
    float s = g3[q] * rsqrtf(v3[q] + 1e-5f);
    W3e[idx] = s * w3[q*480 + o*5 + d3];
  } else if (bid < 1452){
    int i2 = (bid - 1436) * 256 + tid;               // < 4096 exact (W4 fragments)
    int cw = i2 >> 6, kp = i2 & 63;
    int dt = kp >> 4, ch = kp & 15;
    float val = 0.f;
    if (dt < 3){
      float s = g4[cw] * rsqrtf(v4[cw] + 1e-5f);
      val = s * w4[cw*48 + ch*3 + dt];
    }
    int mt = cw >> 4, r = cw & 15, ks = kp >> 5, kq = kp & 31;
    W4f[(ks*4 + mt)*512 + ((kq>>3)*16 + r)*8 + (kq&7)] = f2bf(val);
  } else {
    int t2 = (bid - 1452) * 256 + tid;               // < 512, 448 used
    if (t2 < 272){
      int c = t2 / 17, w = t2 - c * 17;
      float beff = 0.f;
      for (int kk = 0; kk < 5; ++kk){
        float rs = 0.f;
        for (int v = 0; v < 17; ++v) rs += A1[kk*289 + v*17 + w];
        beff += b1[kk*16 + c] * rs;
      }
      float s = g1[t2] * rsqrtf(v1[t2] + 1e-5f);
      bias1f[t2] = s * (beff - m1[t2]) + be1[t2];
    } else if (t2 < 368){
      int cw = t2 - 272;
      int c = cw / 6, w = cw - c * 6;
      float beff = 0.f;
      for (int kk = 0; kk < 5; ++kk){
        float rs = 0.f;
        for (int v = 0; v < 6; ++v) rs += A2[kk*36 + v*6 + w];
        beff += b2[kk*16 + c] * rs;
      }
      float s = g2[cw] * rsqrtf(v2[cw] + 1e-5f);
      bias2f[cw] = s * (beff - m2[cw]) + be2[cw];
    } else if (t2 < 384){
      int o = t2 - 368;
      float s = g3[o] * rsqrtf(v3[o] + 1e-5f);
      bias3f[o] = s * (b3[o] - m3[o]) + be3[o];
    } else if (t2 < 448){
      int o = t2 - 384;
      float s = g4[o] * rsqrtf(v4[o] + 1e-5f);
      bias4f[o] = s * (b4[o] - m4[o]) + be4[o];
    }
  }
}

// ---- prep_B: W32 composition (stride-1 via W2eT) + MFMA-fragment reindex.
// bid <208:        W32[q][d23][p], W32ind[q][d23]
// 208..643:        W1f[272][512] fragments  (boundary fixup stage 1)
// 644..1392:       W2f[96][2496] fragments  (fixup stage 2)
// 1393..1418:      W3f[16][512] fragments   (fixup stage 3)
__global__ void prep_B(const float* __restrict__ W3e, const float* __restrict__ W2e,
                       const float* __restrict__ W2eT, const float* __restrict__ W1e,
                       const float* __restrict__ b2f, const float* __restrict__ b3f,
                       float* __restrict__ W32, float* __restrict__ W32ind,
                       u16* __restrict__ W1f, u16* __restrict__ W2f, u16* __restrict__ W3f)
{
  __shared__ float W3L[480];
  const int bid = blockIdx.x;
  const int tid = threadIdx.x;          // 320
  if (bid < 208){
    const int q = bid / 13, d23 = bid - q * 13;
    for (int i = tid; i < 480; i += 320) W3L[i] = W3e[q*480 + i];
    __syncthreads();
    if (tid < 272){
      float acc = 0.f;
      for (int d3 = 0; d3 < 5; ++d3){
        int d2 = d23 - d3;
        if (d2 < 0 || d2 >= 9) continue;
        const float* w2p = W2eT + (d2*272 + tid)*96;   // stride-1 over o
        const float* wl  = W3L + d3*96;
        float a0=0.f,a1=0.f,a2=0.f,a3=0.f;
        for (int o = 0; o < 96; o += 4){
          a0 += wl[o+0] * w2p[o+0];
          a1 += wl[o+1] * w2p[o+1];
          a2 += wl[o+2] * w2p[o+2];
          a3 += wl[o+3] * w2p[o+3];
        }
        acc += (a0+a1)+(a2+a3);
      }
      W32[bid*272 + tid] = acc;
    } else if (tid == 272){
      float acc = 0.f;
      int d3 = d23 - 4;
      if (d3 >= 0 && d3 < 5)
        for (int o = 0; o < 96; ++o) acc += W3L[d3*96 + o] * b2f[o];
      if (d23 == 6) acc += b3f[q];
      W32ind[bid] = acc;
    }
  } else if (bid < 644){
    int idx = (bid - 208) * 320 + tid;
    if (idx < 139264){
      int cw = idx >> 9, kp = idx & 511;
      int dt = kp / 56, u = kp - dt * 56;
      float val = (dt < 9 && u < 51) ? W1e[(cw*9 + dt)*51 + u] : 0.f;
      int mt = cw >> 4, r = cw & 15, ks = kp >> 5, kq = kp & 31;
      W1f[(ks*17 + mt)*512 + ((kq>>3)*16 + r)*8 + (kq&7)] = f2bf(val);
    }
  } else if (bid < 1393){
    int idx = (bid - 644) * 320 + tid;
    if (idx < 239616){
      int cw = idx / 2496, kp = idx - cw * 2496;
      int dt = kp / 272, pp = kp - dt * 272;
      float val = (dt < 9) ? W2e[(cw*9 + dt)*272 + pp] : 0.f;
      int mt = cw >> 4, r = cw & 15, ks = kp >> 5, kq = kp & 31;
      W2f[(ks*6 + mt)*512 + ((kq>>3)*16 + r)*8 + (kq&7)] = f2bf(val);
    }
  } else {
    int idx = (bid - 1393) * 320 + tid;
    if (idx < 8192){
      int cw = idx >> 9, kp = idx & 511;
      int dt = kp / 96, ch = kp - dt * 96;
      float val = (dt < 5) ? W3e[cw*480 + dt*96 + ch] : 0.f;
      int ks = kp >> 5, kq = kp & 31;
      W3f[ks*512 + ((kq>>3)*16 + cw)*8 + (kq&7)] = f2bf(val);
    }
  }
}

// ---- prep_C: composed conv Wc[q][D<21][uu<51] -> bf16 hi+lo MFMA fragments.
// Uses W1eT for stride-1 inner loop. Interior bias constant biasC[q].
// grid 22 (D; D==21 = padding zero-fill + biasC), block 896.
__global__ void prep_C(const float* __restrict__ W32, const float* __restrict__ W32ind,
                       const float* __restrict__ W1eT, const float* __restrict__ b1f,
                       u16* __restrict__ WcfH, u16* __restrict__ WcfL,
                       float* __restrict__ biasC)
{
  __shared__ float part[208];
  const int D = blockIdx.x;                // 0..21
  const int tid = threadIdx.x;             // 896 = 16*56
  const int q = tid / 56, uu = tid - q * 56;
  if (D == 21){                            // zero-fill padding k' in [1176,1184) + biasC
    if (uu < 8 && q == 0){
      int kp = 1176 + uu;
      int ks = kp >> 5, kq = kp & 31;
      for (int qq = 0; qq < 16; ++qq){
        int pos = ks*512 + ((kq>>3)*16 + qq)*8 + (kq&7);
        WcfH[pos] = 0; WcfL[pos] = 0;
      }
    }
    if (tid < 208){                        // tid = q*13 + d23
      const float* wrow = W32 + tid * 272;
      float s = W32ind[tid];
      float a0=0.f,a1=0.f,a2=0.f,a3=0.f;
      for (int p = 0; p < 272; p += 4){
        a0 += wrow[p+0] * b1f[p+0];
        a1 += wrow[p+1] * b1f[p+1];
        a2 += wrow[p+2] * b1f[p+2];
        a3 += wrow[p+3] * b1f[p+3];
      }
      part[tid] = s + (a0+a1)+(a2+a3);
    }
    __syncthreads();
    if (tid < 16){
      float a = 0.f;
      for (int j = 0; j < 13; ++j) a += part[tid*13 + j];
      biasC[tid] = a;
    }
    return;
  }
  float acc = 0.f;
  if (uu < 51){
    for (int d1 = 0; d1 < 9; ++d1){
      int d23 = D - d1;
      if (d23 < 0 || d23 >= 13) continue;
      const float* wrow = W32 + (q*13 + d23)*272;
      const float* w1r  = W1eT + (d1*51 + uu)*272;   // stride-1 over p
      float a0=0.f,a1=0.f,a2=0.f,a3=0.f;
      for (int p = 0; p < 272; p += 4){
        a0 += wrow[p+0] * w1r[p+0];
        a1 += wrow[p+1] * w1r[p+1];
        a2 += wrow[p+2] * w1r[p+2];
        a3 += wrow[p+3] * w1r[p+3];
      }
      acc += (a0+a1)+(a2+a3);
    }
  }
  int kp = D * 56 + uu;
  int ks = kp >> 5, kq = kp & 31;
  int pos = ks*512 + ((kq>>3)*16 + q)*8 + (kq&7);
  u16 hb = f2bf(acc);
  float hf = __builtin_bit_cast(float, (uint32_t)hb << 16);
  WcfH[pos] = hb;
  WcfL[pos] = f2bf(acc - hf);              // residual -> 2nd MFMA pass (precision)
}

// ---- fused_main: grid (66,16), 256 threads.
// x<2: MFMA boundary fixup (edge e=x), writes out t in [0,7) u [T-7,T).
// x>=2: composed GEMM X0->X3 (37 ksteps, hi+lo, + biasC) + leaky + stage4
//      GEMM + leaky, writes out t in [7, T-7) only (disjoint -> no race).
__launch_bounds__(256)
__global__ void fused_main(const u16* __restrict__ X0, const u16* __restrict__ WcfH,
                           const u16* __restrict__ WcfL, const float* __restrict__ biasC,
                           const u16* __restrict__ W4f, const float* __restrict__ bias4f,
                           const u16* __restrict__ W1f, const u16* __restrict__ W2f,
                           const u16* __restrict__ W3f,
                           const float* __restrict__ b1f, const float* __restrict__ b2f,
                           const float* __restrict__ b3f,
                           float* __restrict__ out)
{
  __shared__ __align__(16) u16 patch[69 * 56];   // interior: X0 rows t0-18 .. t0+50
  __shared__ __align__(16) u16 X3L[48 * 16];     // interior: X3 rows t0-8 .. t0+40
  __shared__ __align__(16) u16 xs [25 * 56];     // fixup: X0 strip
  __shared__ __align__(16) u16 X1s[25 * 272];    // fixup: X1 strip (bf16)
  __shared__ __align__(16) u16 X2s[21 * 96];     // fixup: X2 strip (bf16)
  __shared__ __align__(16) u16 X3s[19 * 16];     // fixup: X3 strip (bf16)

  const int n  = blockIdx.y;
  const int tid = threadIdx.x;
  const int lane = tid & 63;
  const int h    = tid >> 6;
  const int q    = lane >> 4;
  const int l15  = lane & 15;

  if (blockIdx.x < 2){
    // ================= boundary fixup (MFMA) =================
    const int e = blockIdx.x;
    const int base1 = e ? (T_LEN - 14) : 0;
    const int off1 = e ? 0 : 4, off2 = e ? 0 : 2, off3 = e ? 0 : 1;

    // S0: zero-fill strips + stage xs (zero-masked by t range)
    for (int i = tid; i < 1140; i += 256){
      if (i < 850)        *reinterpret_cast<u16x8*>(&X1s[i*8]) = (u16x8)0;
      else if (i < 1102)  *reinterpret_cast<u16x8*>(&X2s[(i-850)*8]) = (u16x8)0;
      else                *reinterpret_cast<u16x8*>(&X3s[(i-1102)*8]) = (u16x8)0;
    }
    for (int idx = tid; idx < 25 * 7; idx += 256){
      int r = idx / 7, g = idx - r * 7;
      int t = base1 + r - 4;
      u16x8 v = (u16x8)0;
      if (t >= 0 && t < T_LEN)
        v = *reinterpret_cast<const u16x8*>(&X0[((size_t)n * T_LEN + t) * 56 + g * 8]);
      *reinterpret_cast<u16x8*>(&xs[r * 56 + g * 8]) = v;
    }
    __syncthreads();

    // S1: X1 strip = W1f (272ch) @ xs.  17 M-tiles over 4 waves, 16 ksteps.
    for (int mt = h; mt < 17; mt += 4){
      f32x4 acc = (f32x4){0.f,0.f,0.f,0.f};
      for (int ks = 0; ks < 16; ++ks){
        bf16x8 aF = *reinterpret_cast<const bf16x8*>(&W1f[(ks*17 + mt)*512 + lane*8]);
        int k0 = ks*32 + q*8;
        int dt = k0 / 56, rr = k0 - dt*56;
        bf16x8 bF = *reinterpret_cast<const bf16x8*>(&xs[(l15 + dt)*56 + rr]);
        acc = __builtin_amdgcn_mfma_f32_16x16x32_bf16(aF, bF, acc, 0, 0, 0);
      }
      if (l15 < 14){
        int chb = mt*16 + q*4;
        ushort4 o;
        o.x = f2bf(acc[0] + b1f[chb+0]); o.y = f2bf(acc[1] + b1f[chb+1]);
        o.z = f2bf(acc[2] + b1f[chb+2]); o.w = f2bf(acc[3] + b1f[chb+3]);
        *reinterpret_cast<ushort4*>(&X1s[(l15 + off1)*272 + chb]) = o;
      }
    }
    __syncthreads();

    // S2: X2 strip = W2f (96ch) @ X1s.  6 M-tiles, 78 ksteps.
    for (int mt = h; mt < 6; mt += 4){
      f32x4 acc = (f32x4){0.f,0.f,0.f,0.f};
      for (int ks = 0; ks < 78; ++ks){
        bf16x8 aF = *reinterpret_cast<const bf16x8*>(&W2f[(ks*6 + mt)*512 + lane*8]);
        int k0 = ks*32 + q*8;
        int dt = k0 / 272, rr = k0 - dt*272;
        bf16x8 bF = *reinterpret_cast<const bf16x8*>(&X1s[(l15 + dt)*272 + rr]);
        acc = __builtin_amdgcn_mfma_f32_16x16x32_bf16(aF, bF, acc, 0, 0, 0);
      }
      if (l15 < 10){
        int chb = mt*16 + q*4;
        ushort4 o;
        o.x = f2bf(acc[0] + b2f[chb+0]); o.y = f2bf(acc[1] + b2f[chb+1]);
        o.z = f2bf(acc[2] + b2f[chb+2]); o.w = f2bf(acc[3] + b2f[chb+3]);
        *reinterpret_cast<ushort4*>(&X2s[(l15 + off2)*96 + chb]) = o;
      }
    }
    __syncthreads();

    // S3: X3 strip = W3f (16ch) @ X2s, leaky. 1 tile (wave 0), 16 ksteps.
    if (h == 0){
      f32x4 acc = (f32x4){0.f,0.f,0.f,0.f};
      for (int ks = 0; ks < 16; ++ks){
        bf16x8 aF = *reinterpret_cast<const bf16x8*>(&W3f[ks*512 + lane*8]);
        int k0 = ks*32 + q*8;
        int dt = k0 / 96, rr = k0 - dt*96;
        bf16x8 bF = *reinterpret_cast<const bf16x8*>(&X2s[(l15 + dt)*96 + rr]);
        acc = __builtin_amdgcn_mfma_f32_16x16x32_bf16(aF, bF, acc, 0, 0, 0);
      }
      if (l15 < 8){
        float v0 = acc[0] + b3f[q*4+0], v1 = acc[1] + b3f[q*4+1];
        float v2 = acc[2] + b3f[q*4+2], v3 = acc[3] + b3f[q*4+3];
        v0 = v0 > 0.f ? v0 : 0.01f*v0; v1 = v1 > 0.f ? v1 : 0.01f*v1;
        v2 = v2 > 0.f ? v2 : 0.01f*v2; v3 = v3 > 0.f ? v3 : 0.01f*v3;
        ushort4 o; o.x = f2bf(v0); o.y = f2bf(v1); o.z = f2bf(v2); o.w = f2bf(v3);
        *reinterpret_cast<ushort4*>(&X3s[(l15 + off3)*16 + q*4]) = o;
      }
    }
    __syncthreads();

    // S4: out strip = W4f (64ch) @ X3s, leaky. wave h = M-tile, 2 ksteps.
    {
      f32x4 acc = (f32x4){0.f,0.f,0.f,0.f};
      for (int ks = 0; ks < 2; ++ks){
        bf16x8 aF = *reinterpret_cast<const bf16x8*>(&W4f[(ks*4 + h)*512 + lane*8]);
        int k0 = ks*32 + q*8;
        int dt2 = k0 >> 4, ch0 = k0 & 15;
        bf16x8 bF = *reinterpret_cast<const bf16x8*>(&X3s[(l15 + dt2)*16 + ch0]);
        acc = __builtin_amdgcn_mfma_f32_16x16x32_bf16(aF, bF, acc, 0, 0, 0);
      }
      if (l15 < 7){
        int chb = h*16 + q*4;
        int t = (e ? (T_LEN - 7) : 0) + l15;
        float v0 = acc[0] + bias4f[chb+0], v1 = acc[1] + bias4f[chb+1];
        float v2 = acc[2] + bias4f[chb+2], v3 = acc[3] + bias4f[chb+3];
        v0 = v0 > 0.f ? v0 : 0.01f*v0; v1 = v1 > 0.f ? v1 : 0.01f*v1;
        v2 = v2 > 0.f ? v2 : 0.01f*v2; v3 = v3 > 0.f ? v3 : 0.01f*v3;
        float4 o; o.x = v0; o.y = v1; o.z = v2; o.w = v3;
        *reinterpret_cast<float4*>(&out[((size_t)n * T_LEN + t) * 64 + chb]) = o;
      }
    }
    return;
  }

  // ================= interior: composed GEMM + stage 4 =================
  const int t0 = (blockIdx.x - 2) * 32;

  for (int idx = tid; idx < 69 * 7; idx += 256){
    int row = idx / 7, g = idx - row * 7;
    int ts = t0 + row - 18;
    u16x8 v = (u16x8)0;
    if (ts >= 0 && ts < T_LEN)
      v = *reinterpret_cast<const u16x8*>(&X0[((size_t)n * T_LEN + ts) * 56 + g * 8]);
    *reinterpret_cast<u16x8*>(&patch[row * 56 + g * 8]) = v;
  }
  __syncthreads();

  // stage A: waves 0-2, each one 16-row X3 tile. 37 ksteps, hi+lo MFMA, dbuf-2.
  if (h < 3){
    f32x4 a0 = (f32x4){0.f, 0.f, 0.f, 0.f};
    bf16x8 aH[2], aL[2], bF[2];
    const u16* bp0 = patch + (16 * h + l15) * 56;
    auto load3 = [&](int buf, int ks){
      const int k0 = ks * 32 + q * 8;
      const int D = k0 / 56, rr = k0 - D * 56;
      aH[buf] = *reinterpret_cast<const bf16x8*>(WcfH + ks * 512 + lane * 8);
      aL[buf] = *reinterpret_cast<const bf16x8*>(WcfL + ks * 512 + lane * 8);
      bF[buf] = *reinterpret_cast<const bf16x8*>(bp0 + D * 56 + rr);
    };
    load3(0, 0);
    for (int ks = 0; ks < 37; ++ks){
      const int cur = ks & 1;
      if (ks + 1 < 37) load3(cur ^ 1, ks + 1);
      a0 = __builtin_amdgcn_mfma_f32_16x16x32_bf16(aH[cur], bF[cur], a0, 0, 0, 0);
      a0 = __builtin_amdgcn_mfma_f32_16x16x32_bf16(aL[cur], bF[cur], a0, 0, 0, 0);
    }
    const float bc0 = biasC[q*4+0], bc1 = biasC[q*4+1], bc2 = biasC[q*4+2], bc3 = biasC[q*4+3];
    int trow = 16 * h + l15;
    int t = t0 - 8 + trow;
    float v0 = a0[0]+bc0, v1 = a0[1]+bc1, v2 = a0[2]+bc2, v3 = a0[3]+bc3;
    v0 = v0 > 0.f ? v0 : 0.01f*v0; v1 = v1 > 0.f ? v1 : 0.01f*v1;
    v2 = v2 > 0.f ? v2 : 0.01f*v2; v3 = v3 > 0.f ? v3 : 0.01f*v3;
    if (t < 0 || t >= T_LEN){ v0 = v1 = v2 = v3 = 0.f; }
    ushort4 o; o.x = f2bf(v0); o.y = f2bf(v1); o.z = f2bf(v2); o.w = f2bf(v3);
    *reinterpret_cast<ushort4*>(&X3L[trow * 16 + q * 4]) = o;
  }
  __syncthreads();

  // stage B: wave h = M-tile (16 of 64 ch), 2 n-tiles, 2 ksteps (K=48 pad 64).
  {
    f32x4 acc[2];
#pragma unroll
    for (int j = 0; j < 2; ++j) acc[j] = (f32x4){0.f, 0.f, 0.f, 0.f};
    bf16x8 aF[2], bF[2][2];
    auto load4 = [&](int buf, int ks){
      const int k0 = ks * 32 + q * 8;
      const int dt2 = k0 >> 4, ch0 = k0 & 15;
      aF[buf] = *reinterpret_cast<const bf16x8*>(W4f + (ks * 4 + h) * 512 + lane * 8);
#pragma unroll
      for (int j = 0; j < 2; ++j)
        bF[buf][j] = *reinterpret_cast<const bf16x8*>(&X3L[(j * 16 + l15 + dt2 + 7) * 16 + ch0]);
    };
    load4(0, 0); load4(1, 1);
#pragma unroll
    for (int j = 0; j < 2; ++j)
      acc[j] = __builtin_amdgcn_mfma_f32_16x16x32_bf16(aF[0], bF[0][j], acc[j], 0, 0, 0);
#pragma unroll
    for (int j = 0; j < 2; ++j)
      acc[j] = __builtin_amdgcn_mfma_f32_16x16x32_bf16(aF[1], bF[1][j], acc[j], 0, 0, 0);

    const int chb = h * 16 + q * 4;
    const float c0 = bias4f[chb+0], c1 = bias4f[chb+1], c2 = bias4f[chb+2], c3 = bias4f[chb+3];
#pragma unroll
    for (int j = 0; j < 2; ++j){
      const int t = t0 + j * 16 + l15;
      float v0 = acc[j][0]+c0, v1 = acc[j][1]+c1, v2 = acc[j][2]+c2, v3 = acc[j][3]+c3;
      v0 = v0 > 0.f ? v0 : 0.01f*v0; v1 = v1 > 0.f ? v1 : 0.01f*v1;
      v2 = v2 > 0.f ? v2 : 0.01f*v2; v3 = v3 > 0.f ? v3 : 0.01f*v3;
      if (t >= 7 && t < T_LEN - 7){            // boundary rows owned by fixup blocks
        float4 o; o.x = v0; o.y = v1; o.z = v2; o.w = v3;
        *reinterpret_cast<float4*>(&out[((size_t)n * T_LEN + t) * 64 + chb]) = o;
      }
    }
  }
}

extern "C" void kernel_launch(void* const* d_in, const int* in_sizes, int n_in,
                              void* d_out, int out_size, void* d_ws, size_t ws_size,
                              hipStream_t stream)
{
  const float* poses = (const float*)d_in[0];
  const float* A1  = (const float*)d_in[1];
  const float* A2  = (const float*)d_in[2];
  const float* w1  = (const float*)d_in[3];
  const float* b1  = (const float*)d_in[4];
  const float* g1  = (const float*)d_in[5];
  const float* be1 = (const float*)d_in[6];
  const float* m1  = (const float*)d_in[7];
  const float* v1  = (const float*)d_in[8];
  const float* w2  = (const float*)d_in[9];
  const float* b2  = (const float*)d_in[10];
  const float* g2  = (const float*)d_in[11];
  const float* be2 = (const float*)d_in[12];
  const float* m2  = (const float*)d_in[13];
  const float* v2  = (const float*)d_in[14];
  const float* w3  = (const float*)d_in[15];
  const float* b3  = (const float*)d_in[16];
  const float* g3  = (const float*)d_in[17];
  const float* be3 = (const float*)d_in[18];
  const float* m3  = (const float*)d_in[19];
  const float* v3  = (const float*)d_in[20];
  const float* w4  = (const float*)d_in[21];
  const float* b4  = (const float*)d_in[22];
  const float* g4  = (const float*)d_in[23];
  const float* be4 = (const float*)d_in[24];
  const float* m4  = (const float*)d_in[25];
  const float* v4  = (const float*)d_in[26];

  uint8_t* ws = (uint8_t*)d_ws;
  size_t off = 0;
  auto alloc = [&](size_t bytes) -> void* {
    void* p = ws + off;
    off += (bytes + 255) & ~(size_t)255;
    return p;
  };
  u16*   X0    = (u16*)  alloc((size_t)NB * T_LEN * 56 * 2);
  float* W1e   = (float*)alloc(124848 * 4);
  float* W1eT  = (float*)alloc(124848 * 4);
  float* W2e   = (float*)alloc(235008 * 4);
  float* W2eT  = (float*)alloc(235008 * 4);
  float* W3e   = (float*)alloc(7680 * 4);
  u16*   W4f   = (u16*)  alloc(4096 * 2);
  float* b1f   = (float*)alloc(272 * 4);
  float* b2f   = (float*)alloc(96 * 4);
  float* b3f   = (float*)alloc(16 * 4);
  float* b4f   = (float*)alloc(64 * 4);
  float* W32   = (float*)alloc(208 * 272 * 4);
  float* W32i  = (float*)alloc(208 * 4);
  u16*   WcfH  = (u16*)  alloc(37 * 512 * 2);
  u16*   WcfL  = (u16*)  alloc(37 * 512 * 2);
  float* biasC = (float*)alloc(16 * 4);
  u16*   W1f   = (u16*)  alloc(139264 * 2);
  u16*   W2f   = (u16*)  alloc(239616 * 2);
  u16*   W3f   = (u16*)  alloc(8192 * 2);

  hipLaunchKernelGGL(conv_poses, dim3(7168), dim3(256), 0, stream, poses, X0);
  hipLaunchKernelGGL(prep_A, dim3(1454), dim3(256), 0, stream,
                     w1, A1, g1, v1, w2, A2, g2, v2, w3, g3, v3, w4, g4, v4,
                     b1, be1, m1, b2, be2, m2, b3, be3, m3, b4, be4, m4,
                     W1e, W1eT, W2e, W2eT, W3e, W4f,
                     b1f, b2f, b3f, b4f);
  hipLaunchKernelGGL(prep_B, dim3(1419), dim3(320), 0, stream,
                     W3e, W2e, W2eT, W1e, b2f, b3f, W32, W32i, W1f, W2f, W3f);
  hipLaunchKernelGGL(prep_C, dim3(22), dim3(896), 0, stream,
                     W32, W32i, W1eT, b1f, WcfH, WcfL, biasC);
  hipLaunchKernelGGL(fused_main, dim3(66, 16), dim3(256), 0, stream,
                     X0, WcfH, WcfL, biasC, W4f, b4f, W1f, W2f, W3f,
                     b1f, b2f, b3f, (float*)d_out);
}

// Round 7
// 189.414 us; speedup vs baseline: 1.8491x; 1.8491x over previous
//
#include <hip/hip_runtime.h>
#include <stdint.h>

typedef unsigned short u16;
typedef __attribute__((ext_vector_type(8))) __bf16 bf16x8;
typedef __attribute__((ext_vector_type(8))) u16 u16x8;
typedef __attribute__((ext_vector_type(4))) float f32x4;

#define T_LEN 2048
#define NB 16

__device__ __forceinline__ u16 f2bf(float f){
  uint32_t x = __builtin_bit_cast(uint32_t, f);
  x += 0x7FFFu + ((x >> 16) & 1u);
  return (u16)(x >> 16);
}

// joint -> (body part, index within part, part length)
__constant__ int c_part[17] = {1,2,3,1,1,4,4,5,5,2,2,3,3,0,0,0,0};
__constant__ int c_pidx[17] = {0,0,0,1,2,0,1,0,1,1,2,1,2,0,1,2,3};
__constant__ int c_plen[17] = {3,3,3,3,3,2,2,2,2,3,3,3,3,4,4,4,4};

// ---- poses fp32 [n][t][51] -> bf16 X0 [n][t][56]; cols 51-55 zero ----
__global__ void conv_poses(const float* __restrict__ poses, u16* __restrict__ X0)
{
  int e = blockIdx.x * 256 + threadIdx.x;          // < 16*2048*56 exact (grid 7168)
  int row = e / 56, c = e - row * 56;
  u16 v = 0;
  if (c < 51) v = f2bf(poses[row * 51 + c]);
  X0[e] = v;
}

// ---- prep_A: per-stage effective weights (fp32, dual layouts) + W4 fragments + biases.
// W1e[(p*9+d1)*51+u], W1eT[(d1*51+u)*272+p]    p<272, d1<9, u<51
// W2e[(o*9+d2)*272+pp], W2eT[(d2*272+pp)*96+o] o<96, d2<9, pp<272
// W3e[q*480 + d3*96 + o]                        q<16, d3<5, o<96
// W4f = bf16 MFMA fragments (stage 4)
__global__ void prep_A(
  const float* __restrict__ w1, const float* __restrict__ A1, const float* __restrict__ g1, const float* __restrict__ v1,
  const float* __restrict__ w2, const float* __restrict__ A2, const float* __restrict__ g2, const float* __restrict__ v2,
  const float* __restrict__ w3, const float* __restrict__ g3, const float* __restrict__ v3,
  const float* __restrict__ w4, const float* __restrict__ g4, const float* __restrict__ v4,
  const float* b1, const float* be1, const float* m1,
  const float* b2, const float* be2, const float* m2,
  const float* b3, const float* be3, const float* m3,
  const float* b4, const float* be4, const float* m4,
  float* __restrict__ W1e, float* __restrict__ W1eT,
  float* __restrict__ W2e, float* __restrict__ W2eT,
  float* __restrict__ W3e, u16* __restrict__ W4f,
  float* bias1f, float* bias2f, float* bias3f, float* bias4f)
{
  const int bid = blockIdx.x;
  const int tid = threadIdx.x;
  if (bid < 488){
    int idx = bid * 256 + tid;
    if (idx < 124848){
      int p = idx / 459, rem = idx - p * 459;
      int d1 = rem / 51, u = rem - d1 * 51;
      int c = p / 17, w = p - c * 17;
      int uj = u / 3, ci = u - uj * 3;
      float val = 0.f;
      for (int kk = 0; kk < 5; ++kk)
        for (int dv = 0; dv < 5; ++dv){
          int v = uj - dv + 2;
          if (v >= 0 && v < 17)
            val += w1[(kk*16 + c)*135 + ci*45 + d1*5 + dv] * A1[kk*289 + v*17 + w];
        }
      val *= g1[p] * rsqrtf(v1[p] + 1e-5f);
      W1e[idx] = val;
      W1eT[(d1*51 + u)*272 + p] = val;
    }
  } else if (bid < 1406){
    int idx = (bid - 488) * 256 + tid;               // < 235008 exact
    int o = idx / 2448, rem = idx - o * 2448;
    int d2 = rem / 272, pp = rem - d2 * 272;
    int c2 = o / 6, w2i = o - c2 * 6;
    int f = pp / 17, J = pp - f * 17;
    int pt = c_part[J];
    int ci = f * c_plen[J] + c_pidx[J];
    float val = 0.f;
    for (int kk = 0; kk < 5; ++kk)
      for (int dv = 0; dv < 3; ++dv){
        int v = pt - dv + 1;
        if (v >= 0 && v < 6)
          val += w2[(kk*16 + c2)*1728 + ci*27 + d2*3 + dv] * A2[kk*36 + v*6 + w2i];
      }
    val *= g2[o] * rsqrtf(v2[o] + 1e-5f);
    W2e[idx] = val;                                   // idx == (o*9+d2)*272+pp
    W2eT[(d2*272 + pp)*96 + o] = val;
  } else if (bid < 1436){
    int idx = (bid - 1406) * 256 + tid;              // < 7680 exact
    int q = idx / 480, rem = idx - q * 480;
    int d3 = rem / 96, o = rem - d3 * 96;
    float s = g3[q] * rsqrtf(v3[q] + 1e-5f);
    W3e[idx] = s * w3[q*480 + o*5 + d3];
  } else if (bid < 1452){
    int i2 = (bid - 1436) * 256 + tid;               // < 4096 exact (W4 fragments)
    int cw = i2 >> 6, kp = i2 & 63;
    int dt = kp >> 4, ch = kp & 15;
    float val = 0.f;
    if (dt < 3){
      float s = g4[cw] * rsqrtf(v4[cw] + 1e-5f);
      val = s * w4[cw*48 + ch*3 + dt];
    }
    int mt = cw >> 4, r = cw & 15, ks = kp >> 5, kq = kp & 31;
    W4f[(ks*4 + mt)*512 + ((kq>>3)*16 + r)*8 + (kq&7)] = f2bf(val);
  } else {
    int t2 = (bid - 1452) * 256 + tid;               // < 512, 448 used
    if (t2 < 272){
      int c = t2 / 17, w = t2 - c * 17;
      float beff = 0.f;
      for (int kk = 0; kk < 5; ++kk){
        float rs = 0.f;
        for (int v = 0; v < 17; ++v) rs += A1[kk*289 + v*17 + w];
        beff += b1[kk*16 + c] * rs;
      }
      float s = g1[t2] * rsqrtf(v1[t2] + 1e-5f);
      bias1f[t2] = s * (beff - m1[t2]) + be1[t2];
    } else if (t2 < 368){
      int cw = t2 - 272;
      int c = cw / 6, w = cw - c * 6;
      float beff = 0.f;
      for (int kk = 0; kk < 5; ++kk){
        float rs = 0.f;
        for (int v = 0; v < 6; ++v) rs += A2[kk*36 + v*6 + w];
        beff += b2[kk*16 + c] * rs;
      }
      float s = g2[cw] * rsqrtf(v2[cw] + 1e-5f);
      bias2f[cw] = s * (beff - m2[cw]) + be2[cw];
    } else if (t2 < 384){
      int o = t2 - 368;
      float s = g3[o] * rsqrtf(v3[o] + 1e-5f);
      bias3f[o] = s * (b3[o] - m3[o]) + be3[o];
    } else if (t2 < 448){
      int o = t2 - 384;
      float s = g4[o] * rsqrtf(v4[o] + 1e-5f);
      bias4f[o] = s * (b4[o] - m4[o]) + be4[o];
    }
  }
}

// ---- prep_B: wave-parallel W32 composition + MFMA-fragment reindex.
// Block 256 = 4 waves. One WAVE per output element; lane-parallel coalesced dot.
// bid <14144:        W32[b=q*13+d23][p]   (wid = bid*4+h < 56576, b=wid/272, p=wid%272)
// 14144..14195:      W32ind (208 waves)
// 14196..14739:      W1f reindex (139264 = 544*256)
// 14740..15675:      W2f reindex (239616 = 936*256)
// 15676..15707:      W3f reindex (8192 = 32*256)
__global__ void prep_B(const float* __restrict__ W3e, const float* __restrict__ W2e,
                       const float* __restrict__ W2eT, const float* __restrict__ W1e,
                       const float* __restrict__ b2f, const float* __restrict__ b3f,
                       float* __restrict__ W32, float* __restrict__ W32ind,
                       u16* __restrict__ W1f, u16* __restrict__ W2f, u16* __restrict__ W3f)
{
  const int bid = blockIdx.x;
  const int tid = threadIdx.x;          // 256
  const int lane = tid & 63;
  const int h = tid >> 6;
  if (bid < 14144){
    int wid = bid * 4 + h;              // < 56576
    int b = wid / 272, p = wid - b * 272;
    int q = b / 13, d23 = b - q * 13;
    float accl = 0.f;
    for (int d3 = 0; d3 < 5; ++d3){
      int d2 = d23 - d3;
      if (d2 < 0 || d2 >= 9) continue;
      const float* w3r = W3e + q*480 + d3*96;        // coalesced over o
      const float* w2r = W2eT + (d2*272 + p)*96;     // coalesced over o
#pragma unroll
      for (int j = 0; j < 2; ++j){
        int o = lane + j*64;
        if (o < 96) accl += w3r[o] * w2r[o];
      }
    }
    for (int m = 32; m > 0; m >>= 1) accl += __shfl_xor(accl, m);
    if (lane == 0) W32[b*272 + p] = accl;
  } else if (bid < 14196){
    int wid = (bid - 14144) * 4 + h;    // < 208
    int q = wid / 13, d23 = wid - q * 13;
    float accl = 0.f;
    int d3 = d23 - 4;
    if (d3 >= 0 && d3 < 5){
      const float* w3r = W3e + q*480 + d3*96;
#pragma unroll
      for (int j = 0; j < 2; ++j){
        int o = lane + j*64;
        if (o < 96) accl += w3r[o] * b2f[o];
      }
    }
    for (int m = 32; m > 0; m >>= 1) accl += __shfl_xor(accl, m);
    if (lane == 0){
      if (d23 == 6) accl += b3f[q];
      W32ind[wid] = accl;
    }
  } else if (bid < 14740){
    int idx = (bid - 14196) * 256 + tid;   // < 139264 exact
    int cw = idx >> 9, kp = idx & 511;
    int dt = kp / 56, u = kp - dt * 56;
    float val = (dt < 9 && u < 51) ? W1e[(cw*9 + dt)*51 + u] : 0.f;
    int mt = cw >> 4, r = cw & 15, ks = kp >> 5, kq = kp & 31;
    W1f[(ks*17 + mt)*512 + ((kq>>3)*16 + r)*8 + (kq&7)] = f2bf(val);
  } else if (bid < 15676){
    int idx = (bid - 14740) * 256 + tid;   // < 239616 exact
    int cw = idx / 2496, kp = idx - cw * 2496;
    int dt = kp / 272, pp = kp - dt * 272;
    float val = (dt < 9) ? W2e[(cw*9 + dt)*272 + pp] : 0.f;
    int mt = cw >> 4, r = cw & 15, ks = kp >> 5, kq = kp & 31;
    W2f[(ks*6 + mt)*512 + ((kq>>3)*16 + r)*8 + (kq&7)] = f2bf(val);
  } else {
    int idx = (bid - 15676) * 256 + tid;   // < 8192 exact
    int cw = idx >> 9, kp = idx & 511;
    int dt = kp / 96, ch = kp - dt * 96;
    float val = (dt < 5) ? W3e[cw*480 + dt*96 + ch] : 0.f;
    int ks = kp >> 5, kq = kp & 31;
    W3f[ks*512 + ((kq>>3)*16 + cw)*8 + (kq&7)] = f2bf(val);
  }
}

// ---- prep_C: wave-parallel composed conv Wc[q][D<21][uu] -> bf16 hi+lo fragments.
// One wave per fragment element (wid = bid*4+h < 18816; q=wid/1176, D=rem/56,
// uu=rem%56; uu>=51 -> zero). Lane-parallel coalesced dot272 over p + butterfly
// reduce. Block 4704 = pad zero-fill (kp 1176..1183 x 16 rows) + biasC (wave/4q).
__global__ void prep_C(const float* __restrict__ W32, const float* __restrict__ W32ind,
                       const float* __restrict__ W1eT, const float* __restrict__ b1f,
                       u16* __restrict__ WcfH, u16* __restrict__ WcfL,
                       float* __restrict__ biasC)
{
  const int tid = threadIdx.x;
  const int lane = tid & 63;
  const int h = tid >> 6;
  if (blockIdx.x == 4704){
    if (tid < 128){
      int kpi = 1176 + (tid >> 4), qq = tid & 15;
      int ks = kpi >> 5, kq = kpi & 31;
      int pos = ks*512 + ((kq>>3)*16 + qq)*8 + (kq&7);
      WcfH[pos] = 0; WcfL[pos] = 0;
    }
    for (int qi = 0; qi < 4; ++qi){
      int q = h*4 + qi;
      float accl = 0.f;
      for (int d23 = 0; d23 < 13; ++d23){
        const float* wrow = W32 + (q*13 + d23)*272;
#pragma unroll
        for (int j = 0; j < 5; ++j){
          int p = lane + j*64;
          if (p < 272) accl += wrow[p] * b1f[p];
        }
      }
      for (int m = 32; m > 0; m >>= 1) accl += __shfl_xor(accl, m);
      if (lane == 0){
        float ind = 0.f;
        for (int d23 = 0; d23 < 13; ++d23) ind += W32ind[q*13 + d23];
        biasC[q] = accl + ind;
      }
    }
    return;
  }
  int wid = blockIdx.x * 4 + h;          // < 18816 exact
  int q = wid / 1176, rem = wid - q * 1176;
  int D = rem / 56, uu = rem - D * 56;
  float accl = 0.f;
  if (uu < 51){
    for (int d1 = 0; d1 < 9; ++d1){
      int d23 = D - d1;
      if (d23 < 0 || d23 >= 13) continue;
      const float* wrow = W32 + (q*13 + d23)*272;     // coalesced over p
      const float* w1r  = W1eT + (d1*51 + uu)*272;    // coalesced over p
#pragma unroll
      for (int j = 0; j < 5; ++j){
        int p = lane + j*64;
        if (p < 272) accl += wrow[p] * w1r[p];
      }
    }
  }
  for (int m = 32; m > 0; m >>= 1) accl += __shfl_xor(accl, m);
  if (lane == 0){
    int kp = D * 56 + uu;
    int ks = kp >> 5, kq = kp & 31;
    int pos = ks*512 + ((kq>>3)*16 + q)*8 + (kq&7);
    u16 hb = f2bf(accl);
    float hf = __builtin_bit_cast(float, (uint32_t)hb << 16);
    WcfH[pos] = hb;
    WcfL[pos] = f2bf(accl - hf);         // residual -> 2nd MFMA pass (precision)
  }
}

// ---- fused_main: grid (66,16), 256 threads.
// x<2: MFMA boundary fixup (edge e=x), writes out t in [0,7) u [T-7,T).
// x>=2: composed GEMM X0->X3 (37 ksteps, hi+lo, + biasC) + leaky + stage4
//      GEMM + leaky, writes out t in [7, T-7) only (disjoint -> no race).
__launch_bounds__(256)
__global__ void fused_main(const u16* __restrict__ X0, const u16* __restrict__ WcfH,
                           const u16* __restrict__ WcfL, const float* __restrict__ biasC,
                           const u16* __restrict__ W4f, const float* __restrict__ bias4f,
                           const u16* __restrict__ W1f, const u16* __restrict__ W2f,
                           const u16* __restrict__ W3f,
                           const float* __restrict__ b1f, const float* __restrict__ b2f,
                           const float* __restrict__ b3f,
                           float* __restrict__ out)
{
  __shared__ __align__(16) u16 patch[69 * 56];   // interior: X0 rows t0-18 .. t0+50
  __shared__ __align__(16) u16 X3L[48 * 16];     // interior: X3 rows t0-8 .. t0+40
  __shared__ __align__(16) u16 xs [25 * 56];     // fixup: X0 strip
  __shared__ __align__(16) u16 X1s[25 * 272];    // fixup: X1 strip (bf16)
  __shared__ __align__(16) u16 X2s[21 * 96];     // fixup: X2 strip (bf16)
  __shared__ __align__(16) u16 X3s[19 * 16];     // fixup: X3 strip (bf16)

  const int n  = blockIdx.y;
  const int tid = threadIdx.x;
  const int lane = tid & 63;
  const int h    = tid >> 6;
  const int q    = lane >> 4;
  const int l15  = lane & 15;

  if (blockIdx.x < 2){
    // ================= boundary fixup (MFMA) =================
    const int e = blockIdx.x;
    const int base1 = e ? (T_LEN - 14) : 0;
    const int off1 = e ? 0 : 4, off2 = e ? 0 : 2, off3 = e ? 0 : 1;

    // S0: zero-fill strips + stage xs (zero-masked by t range)
    for (int i = tid; i < 1140; i += 256){
      if (i < 850)        *reinterpret_cast<u16x8*>(&X1s[i*8]) = (u16x8)0;
      else if (i < 1102)  *reinterpret_cast<u16x8*>(&X2s[(i-850)*8]) = (u16x8)0;
      else                *reinterpret_cast<u16x8*>(&X3s[(i-1102)*8]) = (u16x8)0;
    }
    for (int idx = tid; idx < 25 * 7; idx += 256){
      int r = idx / 7, g = idx - r * 7;
      int t = base1 + r - 4;
      u16x8 v = (u16x8)0;
      if (t >= 0 && t < T_LEN)
        v = *reinterpret_cast<const u16x8*>(&X0[((size_t)n * T_LEN + t) * 56 + g * 8]);
      *reinterpret_cast<u16x8*>(&xs[r * 56 + g * 8]) = v;
    }
    __syncthreads();

    // S1: X1 strip = W1f (272ch) @ xs.  17 M-tiles over 4 waves, 16 ksteps.
    for (int mt = h; mt < 17; mt += 4){
      f32x4 acc = (f32x4){0.f,0.f,0.f,0.f};
      for (int ks = 0; ks < 16; ++ks){
        bf16x8 aF = *reinterpret_cast<const bf16x8*>(&W1f[(ks*17 + mt)*512 + lane*8]);
        int k0 = ks*32 + q*8;
        int dt = k0 / 56, rr = k0 - dt*56;
        bf16x8 bF = *reinterpret_cast<const bf16x8*>(&xs[(l15 + dt)*56 + rr]);
        acc = __builtin_amdgcn_mfma_f32_16x16x32_bf16(aF, bF, acc, 0, 0, 0);
      }
      if (l15 < 14){
        int chb = mt*16 + q*4;
        ushort4 o;
        o.x = f2bf(acc[0] + b1f[chb+0]); o.y = f2bf(acc[1] + b1f[chb+1]);
        o.z = f2bf(acc[2] + b1f[chb+2]); o.w = f2bf(acc[3] + b1f[chb+3]);
        *reinterpret_cast<ushort4*>(&X1s[(l15 + off1)*272 + chb]) = o;
      }
    }
    __syncthreads();

    // S2: X2 strip = W2f (96ch) @ X1s.  6 M-tiles, 78 ksteps.
    for (int mt = h; mt < 6; mt += 4){
      f32x4 acc = (f32x4){0.f,0.f,0.f,0.f};
      for (int ks = 0; ks < 78; ++ks){
        bf16x8 aF = *reinterpret_cast<const bf16x8*>(&W2f[(ks*6 + mt)*512 + lane*8]);
        int k0 = ks*32 + q*8;
        int dt = k0 / 272, rr = k0 - dt*272;
        bf16x8 bF = *reinterpret_cast<const bf16x8*>(&X1s[(l15 + dt)*272 + rr]);
        acc = __builtin_amdgcn_mfma_f32_16x16x32_bf16(aF, bF, acc, 0, 0, 0);
      }
      if (l15 < 10){
        int chb = mt*16 + q*4;
        ushort4 o;
        o.x = f2bf(acc[0] + b2f[chb+0]); o.y = f2bf(acc[1] + b2f[chb+1]);
        o.z = f2bf(acc[2] + b2f[chb+2]); o.w = f2bf(acc[3] + b2f[chb+3]);
        *reinterpret_cast<ushort4*>(&X2s[(l15 + off2)*96 + chb]) = o;
      }
    }
    __syncthreads();

    // S3: X3 strip = W3f (16ch) @ X2s, leaky. 1 tile (wave 0), 16 ksteps.
    if (h == 0){
      f32x4 acc = (f32x4){0.f,0.f,0.f,0.f};
      for (int ks = 0; ks < 16; ++ks){
        bf16x8 aF = *reinterpret_cast<const bf16x8*>(&W3f[ks*512 + lane*8]);
        int k0 = ks*32 + q*8;
        int dt = k0 / 96, rr = k0 - dt*96;
        bf16x8 bF = *reinterpret_cast<const bf16x8*>(&X2s[(l15 + dt)*96 + rr]);
        acc = __builtin_amdgcn_mfma_f32_16x16x32_bf16(aF, bF, acc, 0, 0, 0);
      }
      if (l15 < 8){
        float v0 = acc[0] + b3f[q*4+0], v1 = acc[1] + b3f[q*4+1];
        float v2 = acc[2] + b3f[q*4+2], v3 = acc[3] + b3f[q*4+3];
        v0 = v0 > 0.f ? v0 : 0.01f*v0; v1 = v1 > 0.f ? v1 : 0.01f*v1;
        v2 = v2 > 0.f ? v2 : 0.01f*v2; v3 = v3 > 0.f ? v3 : 0.01f*v3;
        ushort4 o; o.x = f2bf(v0); o.y = f2bf(v1); o.z = f2bf(v2); o.w = f2bf(v3);
        *reinterpret_cast<ushort4*>(&X3s[(l15 + off3)*16 + q*4]) = o;
      }
    }
    __syncthreads();

    // S4: out strip = W4f (64ch) @ X3s, leaky. wave h = M-tile, 2 ksteps.
    {
      f32x4 acc = (f32x4){0.f,0.f,0.f,0.f};
      for (int ks = 0; ks < 2; ++ks){
        bf16x8 aF = *reinterpret_cast<const bf16x8*>(&W4f[(ks*4 + h)*512 + lane*8]);
        int k0 = ks*32 + q*8;
        int dt2 = k0 >> 4, ch0 = k0 & 15;
        bf16x8 bF = *reinterpret_cast<const bf16x8*>(&X3s[(l15 + dt2)*16 + ch0]);
        acc = __builtin_amdgcn_mfma_f32_16x16x32_bf16(aF, bF, acc, 0, 0, 0);
      }
      if (l15 < 7){
        int chb = h*16 + q*4;
        int t = (e ? (T_LEN - 7) : 0) + l15;
        float v0 = acc[0] + bias4f[chb+0], v1 = acc[1] + bias4f[chb+1];
        float v2 = acc[2] + bias4f[chb+2], v3 = acc[3] + bias4f[chb+3];
        v0 = v0 > 0.f ? v0 : 0.01f*v0; v1 = v1 > 0.f ? v1 : 0.01f*v1;
        v2 = v2 > 0.f ? v2 : 0.01f*v2; v3 = v3 > 0.f ? v3 : 0.01f*v3;
        float4 o; o.x = v0; o.y = v1; o.z = v2; o.w = v3;
        *reinterpret_cast<float4*>(&out[((size_t)n * T_LEN + t) * 64 + chb]) = o;
      }
    }
    return;
  }

  // ================= interior: composed GEMM + stage 4 =================
  const int t0 = (blockIdx.x - 2) * 32;

  for (int idx = tid; idx < 69 * 7; idx += 256){
    int row = idx / 7, g = idx - row * 7;
    int ts = t0 + row - 18;
    u16x8 v = (u16x8)0;
    if (ts >= 0 && ts < T_LEN)
      v = *reinterpret_cast<const u16x8*>(&X0[((size_t)n * T_LEN + ts) * 56 + g * 8]);
    *reinterpret_cast<u16x8*>(&patch[row * 56 + g * 8]) = v;
  }
  __syncthreads();

  // stage A: waves 0-2, each one 16-row X3 tile. 37 ksteps, hi+lo MFMA, dbuf-2.
  if (h < 3){
    f32x4 a0 = (f32x4){0.f, 0.f, 0.f, 0.f};
    bf16x8 aH[2], aL[2], bF[2];
    const u16* bp0 = patch + (16 * h + l15) * 56;
    auto load3 = [&](int buf, int ks){
      const int k0 = ks * 32 + q * 8;
      const int D = k0 / 56, rr = k0 - D * 56;
      aH[buf] = *reinterpret_cast<const bf16x8*>(WcfH + ks * 512 + lane * 8);
      aL[buf] = *reinterpret_cast<const bf16x8*>(WcfL + ks * 512 + lane * 8);
      bF[buf] = *reinterpret_cast<const bf16x8*>(bp0 + D * 56 + rr);
    };
    load3(0, 0);
    for (int ks = 0; ks < 37; ++ks){
      const int cur = ks & 1;
      if (ks + 1 < 37) load3(cur ^ 1, ks + 1);
      a0 = __builtin_amdgcn_mfma_f32_16x16x32_bf16(aH[cur], bF[cur], a0, 0, 0, 0);
      a0 = __builtin_amdgcn_mfma_f32_16x16x32_bf16(aL[cur], bF[cur], a0, 0, 0, 0);
    }
    const float bc0 = biasC[q*4+0], bc1 = biasC[q*4+1], bc2 = biasC[q*4+2], bc3 = biasC[q*4+3];
    int trow = 16 * h + l15;
    int t = t0 - 8 + trow;
    float v0 = a0[0]+bc0, v1 = a0[1]+bc1, v2 = a0[2]+bc2, v3 = a0[3]+bc3;
    v0 = v0 > 0.f ? v0 : 0.01f*v0; v1 = v1 > 0.f ? v1 : 0.01f*v1;
    v2 = v2 > 0.f ? v2 : 0.01f*v2; v3 = v3 > 0.f ? v3 : 0.01f*v3;
    if (t < 0 || t >= T_LEN){ v0 = v1 = v2 = v3 = 0.f; }
    ushort4 o; o.x = f2bf(v0); o.y = f2bf(v1); o.z = f2bf(v2); o.w = f2bf(v3);
    *reinterpret_cast<ushort4*>(&X3L[trow * 16 + q * 4]) = o;
  }
  __syncthreads();

  // stage B: wave h = M-tile (16 of 64 ch), 2 n-tiles, 2 ksteps (K=48 pad 64).
  {
    f32x4 acc[2];
#pragma unroll
    for (int j = 0; j < 2; ++j) acc[j] = (f32x4){0.f, 0.f, 0.f, 0.f};
    bf16x8 aF[2], bF[2][2];
    auto load4 = [&](int buf, int ks){
      const int k0 = ks * 32 + q * 8;
      const int dt2 = k0 >> 4, ch0 = k0 & 15;
      aF[buf] = *reinterpret_cast<const bf16x8*>(W4f + (ks * 4 + h) * 512 + lane * 8);
#pragma unroll
      for (int j = 0; j < 2; ++j)
        bF[buf][j] = *reinterpret_cast<const bf16x8*>(&X3L[(j * 16 + l15 + dt2 + 7) * 16 + ch0]);
    };
    load4(0, 0); load4(1, 1);
#pragma unroll
    for (int j = 0; j < 2; ++j)
      acc[j] = __builtin_amdgcn_mfma_f32_16x16x32_bf16(aF[0], bF[0][j], acc[j], 0, 0, 0);
#pragma unroll
    for (int j = 0; j < 2; ++j)
      acc[j] = __builtin_amdgcn_mfma_f32_16x16x32_bf16(aF[1], bF[1][j], acc[j], 0, 0, 0);

    const int chb = h * 16 + q * 4;
    const float c0 = bias4f[chb+0], c1 = bias4f[chb+1], c2 = bias4f[chb+2], c3 = bias4f[chb+3];
#pragma unroll
    for (int j = 0; j < 2; ++j){
      const int t = t0 + j * 16 + l15;
      float v0 = acc[j][0]+c0, v1 = acc[j][1]+c1, v2 = acc[j][2]+c2, v3 = acc[j][3]+c3;
      v0 = v0 > 0.f ? v0 : 0.01f*v0; v1 = v1 > 0.f ? v1 : 0.01f*v1;
      v2 = v2 > 0.f ? v2 : 0.01f*v2; v3 = v3 > 0.f ? v3 : 0.01f*v3;
      if (t >= 7 && t < T_LEN - 7){            // boundary rows owned by fixup blocks
        float4 o; o.x = v0; o.y = v1; o.z = v2; o.w = v3;
        *reinterpret_cast<float4*>(&out[((size_t)n * T_LEN + t) * 64 + chb]) = o;
      }
    }
  }
}

extern "C" void kernel_launch(void* const* d_in, const int* in_sizes, int n_in,
                              void* d_out, int out_size, void* d_ws, size_t ws_size,
                              hipStream_t stream)
{
  const float* poses = (const float*)d_in[0];
  const float* A1  = (const float*)d_in[1];
  const float* A2  = (const float*)d_in[2];
  const float* w1  = (const float*)d_in[3];
  const float* b1  = (const float*)d_in[4];
  const float* g1  = (const float*)d_in[5];
  const float* be1 = (const float*)d_in[6];
  const float* m1  = (const float*)d_in[7];
  const float* v1  = (const float*)d_in[8];
  const float* w2  = (const float*)d_in[9];
  const float* b2  = (const float*)d_in[10];
  const float* g2  = (const float*)d_in[11];
  const float* be2 = (const float*)d_in[12];
  const float* m2  = (const float*)d_in[13];
  const float* v2  = (const float*)d_in[14];
  const float* w3  = (const float*)d_in[15];
  const float* b3  = (const float*)d_in[16];
  const float* g3  = (const float*)d_in[17];
  const float* be3 = (const float*)d_in[18];
  const float* m3  = (const float*)d_in[19];
  const float* v3  = (const float*)d_in[20];
  const float* w4  = (const float*)d_in[21];
  const float* b4  = (const float*)d_in[22];
  const float* g4  = (const float*)d_in[23];
  const float* be4 = (const float*)d_in[24];
  const float* m4  = (const float*)d_in[25];
  const float* v4  = (const float*)d_in[26];

  uint8_t* ws = (uint8_t*)d_ws;
  size_t off = 0;
  auto alloc = [&](size_t bytes) -> void* {
    void* p = ws + off;
    off += (bytes + 255) & ~(size_t)255;
    return p;
  };
  u16*   X0    = (u16*)  alloc((size_t)NB * T_LEN * 56 * 2);
  float* W1e   = (float*)alloc(124848 * 4);
  float* W1eT  = (float*)alloc(124848 * 4);
  float* W2e   = (float*)alloc(235008 * 4);
  float* W2eT  = (float*)alloc(235008 * 4);
  float* W3e   = (float*)alloc(7680 * 4);
  u16*   W4f   = (u16*)  alloc(4096 * 2);
  float* b1f   = (float*)alloc(272 * 4);
  float* b2f   = (float*)alloc(96 * 4);
  float* b3f   = (float*)alloc(16 * 4);
  float* b4f   = (float*)alloc(64 * 4);
  float* W32   = (float*)alloc(208 * 272 * 4);
  float* W32i  = (float*)alloc(208 * 4);
  u16*   WcfH  = (u16*)  alloc(37 * 512 * 2);
  u16*   WcfL  = (u16*)  alloc(37 * 512 * 2);
  float* biasC = (float*)alloc(16 * 4);
  u16*   W1f   = (u16*)  alloc(139264 * 2);
  u16*   W2f   = (u16*)  alloc(239616 * 2);
  u16*   W3f   = (u16*)  alloc(8192 * 2);

  hipLaunchKernelGGL(conv_poses, dim3(7168), dim3(256), 0, stream, poses, X0);
  hipLaunchKernelGGL(prep_A, dim3(1454), dim3(256), 0, stream,
                     w1, A1, g1, v1, w2, A2, g2, v2, w3, g3, v3, w4, g4, v4,
                     b1, be1, m1, b2, be2, m2, b3, be3, m3, b4, be4, m4,
                     W1e, W1eT, W2e, W2eT, W3e, W4f,
                     b1f, b2f, b3f, b4f);
  hipLaunchKernelGGL(prep_B, dim3(15708), dim3(256), 0, stream,
                     W3e, W2e, W2eT, W1e, b2f, b3f, W32, W32i, W1f, W2f, W3f);
  hipLaunchKernelGGL(prep_C, dim3(4705), dim3(256), 0, stream,
                     W32, W32i, W1eT, b1f, WcfH, WcfL, biasC);
  hipLaunchKernelGGL(fused_main, dim3(66, 16), dim3(256), 0, stream,
                     X0, WcfH, WcfL, biasC, W4f, b4f, W1f, W2f, W3f,
                     b1f, b2f, b3f, (float*)d_out);
}